// Round 6
// baseline (459.811 us; speedup 1.0000x reference)
//
#include <hip/hip_runtime.h>
#include <hip/hip_bf16.h>

#define B_   4
#define S_   2048
#define HID_ 1024
#define H_   16
#define D_   64
#define M_   (B_ * S_)

typedef __attribute__((ext_vector_type(8)))  short bf16x8;
typedef __attribute__((ext_vector_type(4)))  float f32x4;
typedef __attribute__((ext_vector_type(16))) float f32x16;

#define GAS __attribute__((address_space(1)))
#define LAS __attribute__((address_space(3)))

__device__ __forceinline__ unsigned short f2bf(float f) {
    union { float f; unsigned int u; } x; x.f = f;
    unsigned int u = x.u;
    return (unsigned short)((u + 0x7fffu + ((u >> 16) & 1u)) >> 16);
}

// ---------------- fused fp32 -> bf16 cast of q,k,v (memory-bound) -----------
__global__ __launch_bounds__(256)
void cast3(const float* __restrict__ q, const float* __restrict__ k, const float* __restrict__ v,
           unsigned short* __restrict__ oq, unsigned short* __restrict__ ok,
           unsigned short* __restrict__ ov) {
    const int sel = blockIdx.x >> 12;          // 4096 blocks per tensor
    const int i = (blockIdx.x & 4095) * 256 + threadIdx.x;   // 8 floats per thread
    const float* in = (sel == 0) ? q : (sel == 1) ? k : v;
    unsigned short* out = (sel == 0) ? oq : (sel == 1) ? ok : ov;
    const f32x4 a = ((const f32x4*)in)[i * 2];
    const f32x4 b = ((const f32x4*)in)[i * 2 + 1];
    bf16x8 w;
#pragma unroll
    for (int j = 0; j < 4; j++) { w[j] = (short)f2bf(a[j]); w[4 + j] = (short)f2bf(b[j]); }
    ((bf16x8*)out)[i] = w;
}

// ---------------- weight transpose + cast: W[k][n] fp32 -> Wt[n][k] bf16 ----
__global__ void transpose_cast(const float* __restrict__ w0, const float* __restrict__ w1,
                               const float* __restrict__ w2, const float* __restrict__ w3,
                               unsigned short* __restrict__ o0, unsigned short* __restrict__ o1,
                               unsigned short* __restrict__ o2, unsigned short* __restrict__ o3) {
    __shared__ float t[32][33];
    const float* w = (blockIdx.z == 0) ? w0 : (blockIdx.z == 1) ? w1 : (blockIdx.z == 2) ? w2 : w3;
    unsigned short* o = (blockIdx.z == 0) ? o0 : (blockIdx.z == 1) ? o1 : (blockIdx.z == 2) ? o2 : o3;
    const int tx = threadIdx.x, ty = threadIdx.y;
    const int bx = blockIdx.x * 32, by = blockIdx.y * 32;
#pragma unroll
    for (int i = 0; i < 4; i++)
        t[ty + i * 8][tx] = w[(size_t)(by + ty + i * 8) * HID_ + bx + tx];
    __syncthreads();
#pragma unroll
    for (int i = 0; i < 4; i++)
        o[(size_t)(bx + ty + i * 8) * HID_ + by + tx] = f2bf(t[tx][ty + i * 8]);
}

// ---------------- fused QKV GEMM, n-pair blocked ----------------------------
// Grid (64, 12): third = y>>2 (0:Q 1:K 2:V), n-pair = y&3 -> n0l = pair*256
// + nt*128 (nt loop). Same m-panel serves both n-tiles (2nd pass L2-hit);
// HW XCD round-robin (linear%8 = x%8) clusters same-m blocks per XCD.
// Role swap: As holds C-row source (weights for Q/K -> rows=n(d); acts for V
// -> rows=m(s)); unified LDS-repack epilogue, coalesced b128 stores.
__global__ __launch_bounds__(256)
void gemm_qkv(const unsigned short* __restrict__ aq, const unsigned short* __restrict__ ak,
              const unsigned short* __restrict__ av, const unsigned short* __restrict__ wqkvT,
              const float* __restrict__ bq, const float* __restrict__ bk,
              const float* __restrict__ bv, unsigned short* __restrict__ Qp,
              unsigned short* __restrict__ Kp, unsigned short* __restrict__ Vt, float cvt) {
    constexpr int BK = 32;
    __shared__ unsigned short smem[8704];    // As[0,4096) Bs[4096,8192); RB aliases all
    unsigned short* As = smem;
    unsigned short* Bs = smem + 4096;

    const int tid  = threadIdx.x;
    const int lane = tid & 63;
    const int wave = tid >> 6;
    const int quad = lane >> 4;
    const int col  = lane & 15;
    const int wr   = (wave & 1) * 64;        // C-row dim (As-source)
    const int wc   = (wave >> 1) * 64;       // C-col dim (Bs-source)
    const int m0   = blockIdx.x * 128;
    const int third = blockIdx.y >> 2;
    const bool vmode = (third == 2);

    const unsigned short* act = (third == 0) ? aq : (third == 1) ? ak : av;
    const float* bias = (third == 0) ? bq : (third == 1) ? bk : bv;
    unsigned short* outp = (third == 0) ? Qp : (third == 1) ? Kp : Vt;
    const float oscale = (third == 0) ? cvt : 1.f;

    const int grow = wave * 16 + (lane >> 2);
    const int gcol = (lane & 3) * 8;
    const unsigned short* agp = act + (size_t)(m0 + grow) * HID_ + gcol;
    unsigned short* asb = &As[wave * 512];
    unsigned short* bsb = &Bs[wave * 512];

    for (int nt = 0; nt < 2; nt++) {
        const int n0l = (blockIdx.y & 3) * 256 + nt * 128;
        const unsigned short* wgp = wqkvT + (size_t)(third * HID_ + n0l + grow) * HID_ + gcol;
        const unsigned short* rgp = vmode ? agp : wgp;   // -> As (C rows)
        const unsigned short* cgp = vmode ? wgp : agp;   // -> Bs (C cols)

        f32x4 zero; zero[0] = 0.f; zero[1] = 0.f; zero[2] = 0.f; zero[3] = 0.f;
        f32x4 acc[4][4];
#pragma unroll
        for (int ri = 0; ri < 4; ri++)
#pragma unroll
            for (int ci = 0; ci < 4; ci++) acc[ri][ci] = zero;

        for (int kt = 0; kt < HID_; kt += BK) {
            __builtin_amdgcn_global_load_lds((const GAS unsigned int*)(rgp + kt),
                                             (LAS unsigned int*)asb, 16, 0, 0);
            __builtin_amdgcn_global_load_lds((const GAS unsigned int*)(rgp + kt + (size_t)64 * HID_),
                                             (LAS unsigned int*)(asb + 2048), 16, 0, 0);
            __builtin_amdgcn_global_load_lds((const GAS unsigned int*)(cgp + kt),
                                             (LAS unsigned int*)bsb, 16, 0, 0);
            __builtin_amdgcn_global_load_lds((const GAS unsigned int*)(cgp + kt + (size_t)64 * HID_),
                                             (LAS unsigned int*)(bsb + 2048), 16, 0, 0);
            __syncthreads();

            bf16x8 af[4], cf[4];
#pragma unroll
            for (int i = 0; i < 4; i++) af[i] = *(const bf16x8*)&As[(wr + i * 16 + col) * BK + quad * 8];
#pragma unroll
            for (int i = 0; i < 4; i++) cf[i] = *(const bf16x8*)&Bs[(wc + i * 16 + col) * BK + quad * 8];
#pragma unroll
            for (int ri = 0; ri < 4; ri++)
#pragma unroll
                for (int ci = 0; ci < 4; ci++)
                    acc[ri][ci] = __builtin_amdgcn_mfma_f32_16x16x32_bf16(af[ri], cf[ci], acc[ri][ci], 0, 0, 0);
            __syncthreads();
        }

        // epilogue: C[r][c], r = wr+ri*16+quad*4+i, c = wc+ci*16+col.
        unsigned short* RB = smem;   // 64 x 136 halves
#pragma unroll
        for (int ph = 0; ph < 2; ph++) {
            if ((wave >> 1) == ph) {
#pragma unroll
                for (int ri = 0; ri < 4; ri++) {
                    f32x4 bv4;
                    if (!vmode) bv4 = *(const f32x4*)&bias[n0l + wr + ri * 16 + quad * 4];
#pragma unroll
                    for (int ci = 0; ci < 4; ci++) {
                        float b0, b1, b2, b3;
                        if (!vmode) { b0 = bv4[0]; b1 = bv4[1]; b2 = bv4[2]; b3 = bv4[3]; }
                        else { b0 = b1 = b2 = b3 = bias[n0l + wc + ci * 16 + col]; }
                        const unsigned int u0 = f2bf((acc[ri][ci][0] + b0) * oscale);
                        const unsigned int u1 = f2bf((acc[ri][ci][1] + b1) * oscale);
                        const unsigned int u2 = f2bf((acc[ri][ci][2] + b2) * oscale);
                        const unsigned int u3 = f2bf((acc[ri][ci][3] + b3) * oscale);
                        uint2 w; w.x = u0 | (u1 << 16); w.y = u2 | (u3 << 16);
                        *(uint2*)&RB[(ci * 16 + col) * 136 + wr + ri * 16 + quad * 4] = w;
                    }
                }
            }
            __syncthreads();
#pragma unroll
            for (int it = 0; it < 4; it++) {
                const int c   = it * 256 + tid;
                const int row = c >> 4, ch = c & 15;
                const bf16x8 v = *(const bf16x8*)&RB[row * 136 + ch * 8];
                if (!vmode) {
                    const int n = n0l + ch * 8;
                    const int h = n >> 6, d = n & 63;
                    const int m = m0 + ph * 64 + row;
                    *(bf16x8*)&outp[(((size_t)(m >> 11) * H_ + h) * S_ + (m & 2047)) * D_ + d] = v;
                } else {
                    const int m = m0 + ch * 8;
                    const int n = n0l + ph * 64 + row;
                    const int h = n >> 6, d = n & 63;
                    *(bf16x8*)&outp[(((size_t)(m >> 11) * H_ + h) * D_ + d) * S_ + (m & 2047)] = v;
                }
            }
            __syncthreads();
        }
    }
}

// ---------------- final GEMM: out[M,N] fp32 = Xc * wo + bo, n-pair blocked --
// Operands swapped (A-frags = weights) so C rows = n: lanes pack f32x4 of 4
// consecutive n, repack via 64x132 fp32 LDS tile, coalesced b128 stores.
// Grid (64, 4): n0l = y*256 + nt*128.
__global__ __launch_bounds__(256)
void gemm_o(const unsigned short* __restrict__ A, const unsigned short* __restrict__ Bt,
            const float* __restrict__ bias, float* __restrict__ outp) {
    constexpr int BK = 32;
    __shared__ float smemf[64 * 132];        // 33.8 KB; As/Bs carved below
    unsigned short* As = (unsigned short*)smemf;
    unsigned short* Bs = As + 4096;

    const int tid  = threadIdx.x;
    const int lane = tid & 63;
    const int wave = tid >> 6;
    const int quad = lane >> 4;
    const int col  = lane & 15;
    const int wn   = (wave >> 1) * 64;   // C-row dim (n, from As=weights)
    const int wm   = (wave & 1) * 64;    // C-col dim (m, from Bs=acts)
    const int m0   = blockIdx.x * 128;

    const int grow = wave * 16 + (lane >> 2);
    const int gcol = (lane & 3) * 8;
    const unsigned short* agp = A + (size_t)(m0 + grow) * HID_ + gcol;
    unsigned short* asb = &As[wave * 512];
    unsigned short* bsb = &Bs[wave * 512];

    for (int nt = 0; nt < 2; nt++) {
        const int n0l = blockIdx.y * 256 + nt * 128;
        const unsigned short* wgp = Bt + (size_t)(n0l + grow) * HID_ + gcol;

        f32x4 zero; zero[0] = 0.f; zero[1] = 0.f; zero[2] = 0.f; zero[3] = 0.f;
        f32x4 acc[4][4];
#pragma unroll
        for (int ri = 0; ri < 4; ri++)
#pragma unroll
            for (int ci = 0; ci < 4; ci++) acc[ri][ci] = zero;

        for (int kt = 0; kt < HID_; kt += BK) {
            __builtin_amdgcn_global_load_lds((const GAS unsigned int*)(wgp + kt),
                                             (LAS unsigned int*)asb, 16, 0, 0);
            __builtin_amdgcn_global_load_lds((const GAS unsigned int*)(wgp + kt + (size_t)64 * HID_),
                                             (LAS unsigned int*)(asb + 2048), 16, 0, 0);
            __builtin_amdgcn_global_load_lds((const GAS unsigned int*)(agp + kt),
                                             (LAS unsigned int*)bsb, 16, 0, 0);
            __builtin_amdgcn_global_load_lds((const GAS unsigned int*)(agp + kt + (size_t)64 * HID_),
                                             (LAS unsigned int*)(bsb + 2048), 16, 0, 0);
            __syncthreads();

            bf16x8 wf[4], af[4];
#pragma unroll
            for (int i = 0; i < 4; i++) wf[i] = *(const bf16x8*)&As[(wn + i * 16 + col) * BK + quad * 8];
#pragma unroll
            for (int i = 0; i < 4; i++) af[i] = *(const bf16x8*)&Bs[(wm + i * 16 + col) * BK + quad * 8];
#pragma unroll
            for (int ri = 0; ri < 4; ri++)
#pragma unroll
                for (int ci = 0; ci < 4; ci++)
                    acc[ri][ci] = __builtin_amdgcn_mfma_f32_16x16x32_bf16(wf[ri], af[ci], acc[ri][ci], 0, 0, 0);
            __syncthreads();
        }

        // epilogue: C[r=n][c=m]; r = wn+ri*16+quad*4+i, c = wm+ci*16+col.
        // Phase over m-halves: pack f32x4 (4 consec n) -> RB[m_local][n], then
        // coalesced fp32 b128 stores (row = one m, 128 consecutive n).
#pragma unroll
        for (int ph = 0; ph < 2; ph++) {
            if ((wave & 1) == ph) {
#pragma unroll
                for (int ri = 0; ri < 4; ri++) {
                    const f32x4 bv4 = *(const f32x4*)&bias[n0l + wn + ri * 16 + quad * 4];
#pragma unroll
                    for (int ci = 0; ci < 4; ci++) {
                        f32x4 v;
#pragma unroll
                        for (int i = 0; i < 4; i++) v[i] = acc[ri][ci][i] + bv4[i];
                        *(f32x4*)&smemf[(ci * 16 + col) * 132 + wn + ri * 16 + quad * 4] = v;
                    }
                }
            }
            __syncthreads();
#pragma unroll
            for (int it = 0; it < 8; it++) {
                const int c   = it * 256 + tid;
                const int row = c >> 5, ch = c & 31;
                const f32x4 v = *(const f32x4*)&smemf[row * 132 + ch * 4];
                *(f32x4*)&outp[(size_t)(m0 + ph * 64 + row) * HID_ + n0l + ch * 4] = v;
            }
            __syncthreads();
        }
    }
}

// ---------------- flash attention v4 (32x32 MFMA) ---------------------------
__global__ __launch_bounds__(256)
void attn_k(const unsigned short* __restrict__ Qp, const unsigned short* __restrict__ Kp,
            const unsigned short* __restrict__ Vt, unsigned short* __restrict__ Xc) {
    constexpr int LT = 72;
    __shared__ unsigned short Ks[64 * LT];       // [key][d]
    __shared__ unsigned short Vs[64 * LT];       // [d][key]
    __shared__ unsigned short Pb[4 * 32 * LT];   // per-wave P [q][key]

    const int tid  = threadIdx.x;
    const int lane = tid & 63;
    const int wave = tid >> 6;
    const int l31  = lane & 31;
    const int hw   = lane >> 5;
    const int bh   = blockIdx.y;
    const int q0   = blockIdx.x * 128 + wave * 32;

    const unsigned short* Qb = Qp + (size_t)bh * S_ * D_;
    const unsigned short* Kb = Kp + (size_t)bh * S_ * D_;
    const unsigned short* Vb = Vt + (size_t)bh * D_ * S_;

    bf16x8 qf[4];
#pragma unroll
    for (int ks = 0; ks < 4; ks++)
        qf[ks] = *(const bf16x8*)&Qb[(q0 + l31) * D_ + ks * 16 + hw * 8];

    f32x16 o[2];
#pragma unroll
    for (int t = 0; t < 2; t++)
#pragma unroll
        for (int i = 0; i < 16; i++) o[t][i] = 0.f;
    float lpart = 0.f;
    unsigned short* Pw = &Pb[wave * 32 * LT];

    for (int c0 = 0; c0 < S_; c0 += 64) {
#pragma unroll
        for (int it = 0; it < 2; it++) {
            const int c = it * 256 + tid;
            const int row = c >> 3, seg = (c & 7) * 8;
            *(bf16x8*)&Ks[row * LT + seg] = *(const bf16x8*)&Kb[(size_t)(c0 + row) * D_ + seg];
            *(bf16x8*)&Vs[row * LT + seg] = *(const bf16x8*)&Vb[(size_t)row * S_ + c0 + seg];
        }
        __syncthreads();

#pragma unroll
        for (int g = 0; g < 2; g++) {
            f32x16 e;
#pragma unroll
            for (int i = 0; i < 16; i++) e[i] = 0.f;
#pragma unroll
            for (int ks = 0; ks < 4; ks++) {
                const bf16x8 a = *(const bf16x8*)&Ks[(g * 32 + l31) * LT + ks * 16 + hw * 8];
                e = __builtin_amdgcn_mfma_f32_32x32x16_bf16(a, qf[ks], e, 0, 0, 0);
            }
#pragma unroll
            for (int grp = 0; grp < 4; grp++) {
                float p0 = __builtin_amdgcn_exp2f(e[grp * 4 + 0]);
                float p1 = __builtin_amdgcn_exp2f(e[grp * 4 + 1]);
                float p2 = __builtin_amdgcn_exp2f(e[grp * 4 + 2]);
                float p3 = __builtin_amdgcn_exp2f(e[grp * 4 + 3]);
                lpart += (p0 + p1) + (p2 + p3);
                const unsigned int u0 = __builtin_bit_cast(unsigned int, p0) + 0x8000u;
                const unsigned int u1 = __builtin_bit_cast(unsigned int, p1) + 0x8000u;
                const unsigned int u2 = __builtin_bit_cast(unsigned int, p2) + 0x8000u;
                const unsigned int u3 = __builtin_bit_cast(unsigned int, p3) + 0x8000u;
                uint2 w;
                w.x = __builtin_amdgcn_perm(u1, u0, 0x07060302u);
                w.y = __builtin_amdgcn_perm(u3, u2, 0x07060302u);
                *(uint2*)&Pw[l31 * LT + g * 32 + grp * 8 + hw * 4] = w;
            }
        }

#pragma unroll
        for (int ks = 0; ks < 4; ks++) {
            const bf16x8 pf = *(const bf16x8*)&Pw[l31 * LT + ks * 16 + hw * 8];
#pragma unroll
            for (int t = 0; t < 2; t++) {
                const bf16x8 vf = *(const bf16x8*)&Vs[(t * 32 + l31) * LT + ks * 16 + hw * 8];
                o[t] = __builtin_amdgcn_mfma_f32_32x32x16_bf16(vf, pf, o[t], 0, 0, 0);
            }
        }
        __syncthreads();
    }

    float l = lpart;
    l += __shfl_xor(l, 32);
    const float inv = 1.f / l;

    const int b = bh >> 4, h = bh & 15;
    const int s = q0 + l31;
    unsigned short* xp = &Xc[((size_t)(b * S_ + s)) * HID_ + h * D_];
#pragma unroll
    for (int t = 0; t < 2; t++)
#pragma unroll
        for (int grp = 0; grp < 4; grp++) {
            const unsigned int u0 = f2bf(o[t][grp * 4 + 0] * inv);
            const unsigned int u1 = f2bf(o[t][grp * 4 + 1] * inv);
            const unsigned int u2 = f2bf(o[t][grp * 4 + 2] * inv);
            const unsigned int u3 = f2bf(o[t][grp * 4 + 3] * inv);
            uint2 w; w.x = u0 | (u1 << 16); w.y = u2 | (u3 << 16);
            *(uint2*)&xp[t * 32 + grp * 8 + hw * 4] = w;
        }
}

// ---------------- launch ----------------------------------------------------
extern "C" void kernel_launch(void* const* d_in, const int* in_sizes, int n_in,
                              void* d_out, int out_size, void* d_ws, size_t ws_size,
                              hipStream_t stream) {
    (void)in_sizes; (void)n_in; (void)out_size; (void)ws_size;
    const float* query = (const float*)d_in[0];
    const float* key   = (const float*)d_in[1];
    const float* value = (const float*)d_in[2];
    const float* wq    = (const float*)d_in[3];
    const float* bq    = (const float*)d_in[4];
    const float* wk    = (const float*)d_in[5];
    const float* bk    = (const float*)d_in[6];
    const float* wv    = (const float*)d_in[7];
    const float* bv    = (const float*)d_in[8];
    const float* wo    = (const float*)d_in[9];
    const float* bo    = (const float*)d_in[10];
    float* out = (float*)d_out;

    unsigned short* ws  = (unsigned short*)d_ws;
    const size_t WSZ = (size_t)HID_ * HID_;   // 1M halves per weight
    const size_t TSZ = (size_t)M_ * HID_;     // 8.4M halves per tensor
    unsigned short* wqkvT = ws;               // wq^T | wk^T | wv^T contiguous
    unsigned short* woT = ws + 3 * WSZ;
    unsigned short* Qp  = woT + WSZ;
    unsigned short* Kp  = Qp + TSZ;
    unsigned short* Vt  = Kp + TSZ;
    unsigned short* Xc  = Vt + TSZ;           // actQ before attn; attn out after
    unsigned short* Xb  = Xc + TSZ;           // actK | actV

    const float cvt = 0.125f * 1.44269504f;   // 1/sqrt(D) * log2(e), folded into Q

    transpose_cast<<<dim3(32, 32, 4), dim3(32, 8), 0, stream>>>(
        wq, wk, wv, wo, wqkvT, wqkvT + WSZ, wqkvT + 2 * WSZ, woT);

    cast3<<<3 * 4096, 256, 0, stream>>>(query, key, value, Xc, Xb, Xb + TSZ);

    gemm_qkv<<<dim3(M_ / 128, 12), 256, 0, stream>>>(
        Xc, Xb, Xb + TSZ, wqkvT, bq, bk, bv, Qp, Kp, Vt, cvt);

    attn_k<<<dim3(S_ / 128, B_ * H_), 256, 0, stream>>>(Qp, Kp, Vt, Xc);

    gemm_o<<<dim3(M_ / 128, 4), 256, 0, stream>>>(Xc, woT, bo, out);
}

// Round 7
// 360.742 us; speedup vs baseline: 1.2746x; 1.2746x over previous
//
#include <hip/hip_runtime.h>
#include <hip/hip_bf16.h>

#define B_   4
#define S_   2048
#define HID_ 1024
#define H_   16
#define D_   64
#define M_   (B_ * S_)

typedef __attribute__((ext_vector_type(8)))  short bf16x8;
typedef __attribute__((ext_vector_type(4)))  float f32x4;
typedef __attribute__((ext_vector_type(16))) float f32x16;

#define GAS __attribute__((address_space(1)))
#define LAS __attribute__((address_space(3)))

__device__ __forceinline__ unsigned short f2bf(float f) {
    union { float f; unsigned int u; } x; x.f = f;
    unsigned int u = x.u;
    return (unsigned short)((u + 0x7fffu + ((u >> 16) & 1u)) >> 16);
}

// ---------------- fused fp32 -> bf16 cast of q,k,v (memory-bound) -----------
__global__ __launch_bounds__(256)
void cast3(const float* __restrict__ q, const float* __restrict__ k, const float* __restrict__ v,
           unsigned short* __restrict__ oq, unsigned short* __restrict__ ok,
           unsigned short* __restrict__ ov) {
    const int sel = blockIdx.x >> 12;          // 4096 blocks per tensor
    const int i = (blockIdx.x & 4095) * 256 + threadIdx.x;   // 8 floats per thread
    const float* in = (sel == 0) ? q : (sel == 1) ? k : v;
    unsigned short* out = (sel == 0) ? oq : (sel == 1) ? ok : ov;
    const f32x4 a = ((const f32x4*)in)[i * 2];
    const f32x4 b = ((const f32x4*)in)[i * 2 + 1];
    bf16x8 w;
#pragma unroll
    for (int j = 0; j < 4; j++) { w[j] = (short)f2bf(a[j]); w[4 + j] = (short)f2bf(b[j]); }
    ((bf16x8*)out)[i] = w;
}

// ---------------- weight transpose + cast: W[k][n] fp32 -> Wt[n][k] bf16 ----
__global__ void transpose_cast(const float* __restrict__ w0, const float* __restrict__ w1,
                               const float* __restrict__ w2, const float* __restrict__ w3,
                               unsigned short* __restrict__ o0, unsigned short* __restrict__ o1,
                               unsigned short* __restrict__ o2, unsigned short* __restrict__ o3) {
    __shared__ float t[32][33];
    const float* w = (blockIdx.z == 0) ? w0 : (blockIdx.z == 1) ? w1 : (blockIdx.z == 2) ? w2 : w3;
    unsigned short* o = (blockIdx.z == 0) ? o0 : (blockIdx.z == 1) ? o1 : (blockIdx.z == 2) ? o2 : o3;
    const int tx = threadIdx.x, ty = threadIdx.y;
    const int bx = blockIdx.x * 32, by = blockIdx.y * 32;
#pragma unroll
    for (int i = 0; i < 4; i++)
        t[ty + i * 8][tx] = w[(size_t)(by + ty + i * 8) * HID_ + bx + tx];
    __syncthreads();
#pragma unroll
    for (int i = 0; i < 4; i++)
        o[(size_t)(bx + ty + i * 8) * HID_ + by + tx] = f2bf(t[tx][ty + i * 8]);
}

// ---------------- fused QKV GEMM (R5 grid; occupancy-capped) ----------------
// Grid (64, 24): third = y>>3 (0:Q 1:K 2:V), n0l = (y&7)*128.
// Role swap: As holds C-row source (weights for Q/K -> rows=n(d), coalesced
// [B,H,S,D] stores; acts for V -> rows=m(s), coalesced [B,H,D,S] stores).
// __launch_bounds__(256,3): 3 blocks/CU (170-reg cap) for load MLP.
__global__ __launch_bounds__(256, 3)
void gemm_qkv(const unsigned short* __restrict__ aq, const unsigned short* __restrict__ ak,
              const unsigned short* __restrict__ av, const unsigned short* __restrict__ wqkvT,
              const float* __restrict__ bq, const float* __restrict__ bk,
              const float* __restrict__ bv, unsigned short* __restrict__ Qp,
              unsigned short* __restrict__ Kp, unsigned short* __restrict__ Vt, float cvt) {
    constexpr int BK = 32;
    __shared__ unsigned short smem[8704];    // As[0,4096) Bs[4096,8192); RB aliases all
    unsigned short* As = smem;
    unsigned short* Bs = smem + 4096;

    const int tid  = threadIdx.x;
    const int lane = tid & 63;
    const int wave = tid >> 6;
    const int quad = lane >> 4;
    const int col  = lane & 15;
    const int wr   = (wave & 1) * 64;        // C-row dim (As-source)
    const int wc   = (wave >> 1) * 64;       // C-col dim (Bs-source)
    const int m0   = blockIdx.x * 128;
    const int third = blockIdx.y >> 3;
    const int n0l   = (blockIdx.y & 7) * 128;
    const bool vmode = (third == 2);

    const unsigned short* act = (third == 0) ? aq : (third == 1) ? ak : av;
    const float* bias = (third == 0) ? bq : (third == 1) ? bk : bv;
    unsigned short* outp = (third == 0) ? Qp : (third == 1) ? Kp : Vt;
    const float oscale = (third == 0) ? cvt : 1.f;

    const int grow = wave * 16 + (lane >> 2);
    const int gcol = (lane & 3) * 8;
    const unsigned short* wgp = wqkvT + (size_t)(third * HID_ + n0l + grow) * HID_ + gcol;
    const unsigned short* agp = act + (size_t)(m0 + grow) * HID_ + gcol;
    const unsigned short* rgp = vmode ? agp : wgp;   // -> As (C rows)
    const unsigned short* cgp = vmode ? wgp : agp;   // -> Bs (C cols)
    unsigned short* asb = &As[wave * 512];
    unsigned short* bsb = &Bs[wave * 512];

    f32x4 zero; zero[0] = 0.f; zero[1] = 0.f; zero[2] = 0.f; zero[3] = 0.f;
    f32x4 acc[4][4];
#pragma unroll
    for (int ri = 0; ri < 4; ri++)
#pragma unroll
        for (int ci = 0; ci < 4; ci++) acc[ri][ci] = zero;

    for (int kt = 0; kt < HID_; kt += BK) {
        __builtin_amdgcn_global_load_lds((const GAS unsigned int*)(rgp + kt),
                                         (LAS unsigned int*)asb, 16, 0, 0);
        __builtin_amdgcn_global_load_lds((const GAS unsigned int*)(rgp + kt + (size_t)64 * HID_),
                                         (LAS unsigned int*)(asb + 2048), 16, 0, 0);
        __builtin_amdgcn_global_load_lds((const GAS unsigned int*)(cgp + kt),
                                         (LAS unsigned int*)bsb, 16, 0, 0);
        __builtin_amdgcn_global_load_lds((const GAS unsigned int*)(cgp + kt + (size_t)64 * HID_),
                                         (LAS unsigned int*)(bsb + 2048), 16, 0, 0);
        __syncthreads();

        bf16x8 af[4], cf[4];
#pragma unroll
        for (int i = 0; i < 4; i++) af[i] = *(const bf16x8*)&As[(wr + i * 16 + col) * BK + quad * 8];
#pragma unroll
        for (int i = 0; i < 4; i++) cf[i] = *(const bf16x8*)&Bs[(wc + i * 16 + col) * BK + quad * 8];
#pragma unroll
        for (int ri = 0; ri < 4; ri++)
#pragma unroll
            for (int ci = 0; ci < 4; ci++)
                acc[ri][ci] = __builtin_amdgcn_mfma_f32_16x16x32_bf16(af[ri], cf[ci], acc[ri][ci], 0, 0, 0);
        __syncthreads();
    }

    // epilogue: C[r][c], r = wr+ri*16+quad*4+i, c = wc+ci*16+col.
    unsigned short* RB = smem;   // 64 x 136 halves
#pragma unroll
    for (int ph = 0; ph < 2; ph++) {
        if ((wave >> 1) == ph) {
#pragma unroll
            for (int ri = 0; ri < 4; ri++) {
                f32x4 bv4;
                if (!vmode) bv4 = *(const f32x4*)&bias[n0l + wr + ri * 16 + quad * 4];
#pragma unroll
                for (int ci = 0; ci < 4; ci++) {
                    float b0, b1, b2, b3;
                    if (!vmode) { b0 = bv4[0]; b1 = bv4[1]; b2 = bv4[2]; b3 = bv4[3]; }
                    else { b0 = b1 = b2 = b3 = bias[n0l + wc + ci * 16 + col]; }
                    const unsigned int u0 = f2bf((acc[ri][ci][0] + b0) * oscale);
                    const unsigned int u1 = f2bf((acc[ri][ci][1] + b1) * oscale);
                    const unsigned int u2 = f2bf((acc[ri][ci][2] + b2) * oscale);
                    const unsigned int u3 = f2bf((acc[ri][ci][3] + b3) * oscale);
                    uint2 w; w.x = u0 | (u1 << 16); w.y = u2 | (u3 << 16);
                    *(uint2*)&RB[(ci * 16 + col) * 136 + wr + ri * 16 + quad * 4] = w;
                }
            }
        }
        __syncthreads();
#pragma unroll
        for (int it = 0; it < 4; it++) {
            const int c   = it * 256 + tid;
            const int row = c >> 4, ch = c & 15;
            const bf16x8 v = *(const bf16x8*)&RB[row * 136 + ch * 8];
            if (!vmode) {
                const int n = n0l + ch * 8;
                const int h = n >> 6, d = n & 63;
                const int m = m0 + ph * 64 + row;
                *(bf16x8*)&outp[(((size_t)(m >> 11) * H_ + h) * S_ + (m & 2047)) * D_ + d] = v;
            } else {
                const int m = m0 + ch * 8;
                const int n = n0l + ph * 64 + row;
                const int h = n >> 6, d = n & 63;
                *(bf16x8*)&outp[(((size_t)(m >> 11) * H_ + h) * D_ + d) * S_ + (m & 2047)] = v;
            }
        }
        __syncthreads();
    }
}

// ---------------- final GEMM: out[M,N] fp32 = Xc * wo + bo ------------------
// Grid (64, 8). Operands swapped (A-frags = weights) so C rows = n: lanes
// pack f32x4 of 4 consecutive n, repack via 64x132 fp32 LDS tile, coalesced
// b128 stores. __launch_bounds__(256,3) for load MLP.
__global__ __launch_bounds__(256, 3)
void gemm_o(const unsigned short* __restrict__ A, const unsigned short* __restrict__ Bt,
            const float* __restrict__ bias, float* __restrict__ outp) {
    constexpr int BK = 32;
    __shared__ float smemf[64 * 132];        // 33.8 KB; As/Bs carved below
    unsigned short* As = (unsigned short*)smemf;
    unsigned short* Bs = As + 4096;

    const int tid  = threadIdx.x;
    const int lane = tid & 63;
    const int wave = tid >> 6;
    const int quad = lane >> 4;
    const int col  = lane & 15;
    const int wn   = (wave >> 1) * 64;   // C-row dim (n, from As=weights)
    const int wm   = (wave & 1) * 64;    // C-col dim (m, from Bs=acts)
    const int m0   = blockIdx.x * 128;
    const int n0l  = blockIdx.y * 128;

    const int grow = wave * 16 + (lane >> 2);
    const int gcol = (lane & 3) * 8;
    const unsigned short* agp = A + (size_t)(m0 + grow) * HID_ + gcol;
    const unsigned short* wgp = Bt + (size_t)(n0l + grow) * HID_ + gcol;
    unsigned short* asb = &As[wave * 512];
    unsigned short* bsb = &Bs[wave * 512];

    f32x4 zero; zero[0] = 0.f; zero[1] = 0.f; zero[2] = 0.f; zero[3] = 0.f;
    f32x4 acc[4][4];
#pragma unroll
    for (int ri = 0; ri < 4; ri++)
#pragma unroll
        for (int ci = 0; ci < 4; ci++) acc[ri][ci] = zero;

    for (int kt = 0; kt < HID_; kt += BK) {
        __builtin_amdgcn_global_load_lds((const GAS unsigned int*)(wgp + kt),
                                         (LAS unsigned int*)asb, 16, 0, 0);
        __builtin_amdgcn_global_load_lds((const GAS unsigned int*)(wgp + kt + (size_t)64 * HID_),
                                         (LAS unsigned int*)(asb + 2048), 16, 0, 0);
        __builtin_amdgcn_global_load_lds((const GAS unsigned int*)(agp + kt),
                                         (LAS unsigned int*)bsb, 16, 0, 0);
        __builtin_amdgcn_global_load_lds((const GAS unsigned int*)(agp + kt + (size_t)64 * HID_),
                                         (LAS unsigned int*)(bsb + 2048), 16, 0, 0);
        __syncthreads();

        bf16x8 wf[4], af[4];
#pragma unroll
        for (int i = 0; i < 4; i++) wf[i] = *(const bf16x8*)&As[(wn + i * 16 + col) * BK + quad * 8];
#pragma unroll
        for (int i = 0; i < 4; i++) af[i] = *(const bf16x8*)&Bs[(wm + i * 16 + col) * BK + quad * 8];
#pragma unroll
        for (int ri = 0; ri < 4; ri++)
#pragma unroll
            for (int ci = 0; ci < 4; ci++)
                acc[ri][ci] = __builtin_amdgcn_mfma_f32_16x16x32_bf16(wf[ri], af[ci], acc[ri][ci], 0, 0, 0);
        __syncthreads();
    }

    // epilogue: C[r=n][c=m]; pack f32x4 (4 consec n) -> RB[m_local][n], then
    // coalesced fp32 b128 stores (row = one m, 128 consecutive n).
#pragma unroll
    for (int ph = 0; ph < 2; ph++) {
        if ((wave & 1) == ph) {
#pragma unroll
            for (int ri = 0; ri < 4; ri++) {
                const f32x4 bv4 = *(const f32x4*)&bias[n0l + wn + ri * 16 + quad * 4];
#pragma unroll
                for (int ci = 0; ci < 4; ci++) {
                    f32x4 v;
#pragma unroll
                    for (int i = 0; i < 4; i++) v[i] = acc[ri][ci][i] + bv4[i];
                    *(f32x4*)&smemf[(ci * 16 + col) * 132 + wn + ri * 16 + quad * 4] = v;
                }
            }
        }
        __syncthreads();
#pragma unroll
        for (int it = 0; it < 8; it++) {
            const int c   = it * 256 + tid;
            const int row = c >> 5, ch = c & 31;
            const f32x4 v = *(const f32x4*)&smemf[row * 132 + ch * 4];
            *(f32x4*)&outp[(size_t)(m0 + ph * 64 + row) * HID_ + n0l + ch * 4] = v;
        }
        __syncthreads();
    }
}

// ---------------- flash attention v4 (32x32 MFMA) ---------------------------
__global__ __launch_bounds__(256)
void attn_k(const unsigned short* __restrict__ Qp, const unsigned short* __restrict__ Kp,
            const unsigned short* __restrict__ Vt, unsigned short* __restrict__ Xc) {
    constexpr int LT = 72;
    __shared__ unsigned short Ks[64 * LT];       // [key][d]
    __shared__ unsigned short Vs[64 * LT];       // [d][key]
    __shared__ unsigned short Pb[4 * 32 * LT];   // per-wave P [q][key]

    const int tid  = threadIdx.x;
    const int lane = tid & 63;
    const int wave = tid >> 6;
    const int l31  = lane & 31;
    const int hw   = lane >> 5;
    const int bh   = blockIdx.y;
    const int q0   = blockIdx.x * 128 + wave * 32;

    const unsigned short* Qb = Qp + (size_t)bh * S_ * D_;
    const unsigned short* Kb = Kp + (size_t)bh * S_ * D_;
    const unsigned short* Vb = Vt + (size_t)bh * D_ * S_;

    bf16x8 qf[4];
#pragma unroll
    for (int ks = 0; ks < 4; ks++)
        qf[ks] = *(const bf16x8*)&Qb[(q0 + l31) * D_ + ks * 16 + hw * 8];

    f32x16 o[2];
#pragma unroll
    for (int t = 0; t < 2; t++)
#pragma unroll
        for (int i = 0; i < 16; i++) o[t][i] = 0.f;
    float lpart = 0.f;
    unsigned short* Pw = &Pb[wave * 32 * LT];

    for (int c0 = 0; c0 < S_; c0 += 64) {
#pragma unroll
        for (int it = 0; it < 2; it++) {
            const int c = it * 256 + tid;
            const int row = c >> 3, seg = (c & 7) * 8;
            *(bf16x8*)&Ks[row * LT + seg] = *(const bf16x8*)&Kb[(size_t)(c0 + row) * D_ + seg];
            *(bf16x8*)&Vs[row * LT + seg] = *(const bf16x8*)&Vb[(size_t)row * S_ + c0 + seg];
        }
        __syncthreads();

#pragma unroll
        for (int g = 0; g < 2; g++) {
            f32x16 e;
#pragma unroll
            for (int i = 0; i < 16; i++) e[i] = 0.f;
#pragma unroll
            for (int ks = 0; ks < 4; ks++) {
                const bf16x8 a = *(const bf16x8*)&Ks[(g * 32 + l31) * LT + ks * 16 + hw * 8];
                e = __builtin_amdgcn_mfma_f32_32x32x16_bf16(a, qf[ks], e, 0, 0, 0);
            }
#pragma unroll
            for (int grp = 0; grp < 4; grp++) {
                float p0 = __builtin_amdgcn_exp2f(e[grp * 4 + 0]);
                float p1 = __builtin_amdgcn_exp2f(e[grp * 4 + 1]);
                float p2 = __builtin_amdgcn_exp2f(e[grp * 4 + 2]);
                float p3 = __builtin_amdgcn_exp2f(e[grp * 4 + 3]);
                lpart += (p0 + p1) + (p2 + p3);
                const unsigned int u0 = __builtin_bit_cast(unsigned int, p0) + 0x8000u;
                const unsigned int u1 = __builtin_bit_cast(unsigned int, p1) + 0x8000u;
                const unsigned int u2 = __builtin_bit_cast(unsigned int, p2) + 0x8000u;
                const unsigned int u3 = __builtin_bit_cast(unsigned int, p3) + 0x8000u;
                uint2 w;
                w.x = __builtin_amdgcn_perm(u1, u0, 0x07060302u);
                w.y = __builtin_amdgcn_perm(u3, u2, 0x07060302u);
                *(uint2*)&Pw[l31 * LT + g * 32 + grp * 8 + hw * 4] = w;
            }
        }

#pragma unroll
        for (int ks = 0; ks < 4; ks++) {
            const bf16x8 pf = *(const bf16x8*)&Pw[l31 * LT + ks * 16 + hw * 8];
#pragma unroll
            for (int t = 0; t < 2; t++) {
                const bf16x8 vf = *(const bf16x8*)&Vs[(t * 32 + l31) * LT + ks * 16 + hw * 8];
                o[t] = __builtin_amdgcn_mfma_f32_32x32x16_bf16(vf, pf, o[t], 0, 0, 0);
            }
        }
        __syncthreads();
    }

    float l = lpart;
    l += __shfl_xor(l, 32);
    const float inv = 1.f / l;

    const int b = bh >> 4, h = bh & 15;
    const int s = q0 + l31;
    unsigned short* xp = &Xc[((size_t)(b * S_ + s)) * HID_ + h * D_];
#pragma unroll
    for (int t = 0; t < 2; t++)
#pragma unroll
        for (int grp = 0; grp < 4; grp++) {
            const unsigned int u0 = f2bf(o[t][grp * 4 + 0] * inv);
            const unsigned int u1 = f2bf(o[t][grp * 4 + 1] * inv);
            const unsigned int u2 = f2bf(o[t][grp * 4 + 2] * inv);
            const unsigned int u3 = f2bf(o[t][grp * 4 + 3] * inv);
            uint2 w; w.x = u0 | (u1 << 16); w.y = u2 | (u3 << 16);
            *(uint2*)&xp[t * 32 + grp * 8 + hw * 4] = w;
        }
}

// ---------------- launch ----------------------------------------------------
extern "C" void kernel_launch(void* const* d_in, const int* in_sizes, int n_in,
                              void* d_out, int out_size, void* d_ws, size_t ws_size,
                              hipStream_t stream) {
    (void)in_sizes; (void)n_in; (void)out_size; (void)ws_size;
    const float* query = (const float*)d_in[0];
    const float* key   = (const float*)d_in[1];
    const float* value = (const float*)d_in[2];
    const float* wq    = (const float*)d_in[3];
    const float* bq    = (const float*)d_in[4];
    const float* wk    = (const float*)d_in[5];
    const float* bk    = (const float*)d_in[6];
    const float* wv    = (const float*)d_in[7];
    const float* bv    = (const float*)d_in[8];
    const float* wo    = (const float*)d_in[9];
    const float* bo    = (const float*)d_in[10];
    float* out = (float*)d_out;

    unsigned short* ws  = (unsigned short*)d_ws;
    const size_t WSZ = (size_t)HID_ * HID_;   // 1M halves per weight
    const size_t TSZ = (size_t)M_ * HID_;     // 8.4M halves per tensor
    unsigned short* wqkvT = ws;               // wq^T | wk^T | wv^T contiguous
    unsigned short* woT = ws + 3 * WSZ;
    unsigned short* Qp  = woT + WSZ;
    unsigned short* Kp  = Qp + TSZ;
    unsigned short* Vt  = Kp + TSZ;
    unsigned short* Xc  = Vt + TSZ;           // actQ before attn; attn out after
    unsigned short* Xb  = Xc + TSZ;           // actK | actV

    const float cvt = 0.125f * 1.44269504f;   // 1/sqrt(D) * log2(e), folded into Q

    transpose_cast<<<dim3(32, 32, 4), dim3(32, 8), 0, stream>>>(
        wq, wk, wv, wo, wqkvT, wqkvT + WSZ, wqkvT + 2 * WSZ, woT);

    cast3<<<3 * 4096, 256, 0, stream>>>(query, key, value, Xc, Xb, Xb + TSZ);

    gemm_qkv<<<dim3(M_ / 128, 24), 256, 0, stream>>>(
        Xc, Xb, Xb + TSZ, wqkvT, bq, bk, bv, Qp, Kp, Vt, cvt);

    attn_k<<<dim3(S_ / 128, B_ * H_), 256, 0, stream>>>(Qp, Kp, Vt, Xc);

    gemm_o<<<dim3(M_ / 128, 8), 256, 0, stream>>>(Xc, woT, bo, out);
}